// Round 1
// baseline (1531.012 us; speedup 1.0000x reference)
//
#include <hip/hip_runtime.h>
#include <hip/hip_bf16.h>

#define N_USER_C 100000
#define N_ITEM_C 100000
#define D_C 64
#define NN_C (N_USER_C + N_ITEM_C)
#define ND_C (NN_C * D_C)   /* 12,800,000 floats */

// ---- CSR build ------------------------------------------------------------

__global__ void count_kernel(const int* __restrict__ row, int* __restrict__ cnt, int nnz) {
    int stride = gridDim.x * blockDim.x;
    for (int e = blockIdx.x * blockDim.x + threadIdx.x; e < nnz; e += stride)
        atomicAdd(&cnt[row[e]], 1);
}

// Single-block exclusive scan of cnt[0..n) -> row_ptr[0..n]; row_ptr[n]=nnz.
__global__ void scan_kernel(const int* __restrict__ cnt, int* __restrict__ row_ptr,
                            int n, int nnz) {
    __shared__ int s[1024];
    int t = threadIdx.x;
    int items = (n + 1023) / 1024;
    int base = t * items;
    int end = base + items; if (end > n) end = n;
    int sum = 0;
    for (int i = base; i < end; ++i) sum += cnt[i];
    s[t] = sum;
    __syncthreads();
    for (int off = 1; off < 1024; off <<= 1) {
        int v = (t >= off) ? s[t - off] : 0;
        __syncthreads();
        s[t] += v;
        __syncthreads();
    }
    int run = (t == 0) ? 0 : s[t - 1];
    for (int i = base; i < end; ++i) { row_ptr[i] = run; run += cnt[i]; }
    if (t == 0) row_ptr[n] = nnz;
}

__global__ void scatter_kernel(const int* __restrict__ row, const int* __restrict__ col,
                               const float* __restrict__ val, const int* __restrict__ row_ptr,
                               int* __restrict__ fill, int* __restrict__ csr_col,
                               float* __restrict__ csr_val, int nnz) {
    int stride = gridDim.x * blockDim.x;
    for (int e = blockIdx.x * blockDim.x + threadIdx.x; e < nnz; e += stride) {
        int r = row[e];
        int p = atomicAdd(&fill[r], 1);
        int idx = row_ptr[r] + p;
        csr_col[idx] = col[e];
        csr_val[idx] = val[e];
    }
}

// ---- propagation ----------------------------------------------------------

__global__ void init_kernel(const float4* __restrict__ uw, const float4* __restrict__ iw,
                            float4* __restrict__ h, float4* __restrict__ out_acc,
                            int nu4, int tot4) {
    int stride = gridDim.x * blockDim.x;
    for (int i = blockIdx.x * blockDim.x + threadIdx.x; i < tot4; i += stride) {
        float4 v = (i < nu4) ? uw[i] : iw[i - nu4];
        h[i] = v;
        out_acc[i] = v;
    }
}

// One 16-lane group per row; lane l owns floats [4l, 4l+4). Gather 256B/edge
// coalesced, fused row-norm (shfl reduce within 16-lane group) and
// out_acc += coef * h_normalized.
__global__ __launch_bounds__(256) void spmv_kernel(
        const float* __restrict__ hin, float* __restrict__ hout,
        float* __restrict__ out_acc, const int* __restrict__ row_ptr,
        const int* __restrict__ csr_col, const float* __restrict__ csr_val,
        float coef) {
    int gid = blockIdx.x * blockDim.x + threadIdx.x;
    int r = gid >> 4;
    int l = gid & 15;
    if (r >= NN_C) return;
    int e0 = row_ptr[r], e1 = row_ptr[r + 1];
    float4 acc = make_float4(0.f, 0.f, 0.f, 0.f);
    for (int e = e0; e < e1; ++e) {
        int c = csr_col[e];
        float v = csr_val[e];
        const float4 hv = *reinterpret_cast<const float4*>(hin + (size_t)c * 64 + l * 4);
        acc.x += v * hv.x; acc.y += v * hv.y; acc.z += v * hv.z; acc.w += v * hv.w;
    }
    float ss = acc.x * acc.x + acc.y * acc.y + acc.z * acc.z + acc.w * acc.w;
    ss += __shfl_xor(ss, 1);
    ss += __shfl_xor(ss, 2);
    ss += __shfl_xor(ss, 4);
    ss += __shfl_xor(ss, 8);
    float scale = 1.0f / fmaxf(sqrtf(ss), 1e-12f);
    float4 hn = make_float4(acc.x * scale, acc.y * scale, acc.z * scale, acc.w * scale);
    size_t o = (size_t)r * 64 + l * 4;
    *reinterpret_cast<float4*>(hout + o) = hn;
    float4* oa = reinterpret_cast<float4*>(out_acc + o);
    float4 cur = *oa;
    cur.x += coef * hn.x; cur.y += coef * hn.y;
    cur.z += coef * hn.z; cur.w += coef * hn.w;
    *oa = cur;
}

// ---- losses ---------------------------------------------------------------

__global__ void ssq_kernel(const float4* __restrict__ uw, const float4* __restrict__ iw,
                           float* __restrict__ accums, int n4) {
    int stride = gridDim.x * blockDim.x;
    float su = 0.f, si = 0.f;
    int tot = 2 * n4;
    for (int i = blockIdx.x * blockDim.x + threadIdx.x; i < tot; i += stride) {
        float4 v = (i < n4) ? uw[i] : iw[i - n4];
        float d = v.x * v.x + v.y * v.y + v.z * v.z + v.w * v.w;
        if (i < n4) su += d; else si += d;
    }
    #pragma unroll
    for (int o = 1; o < 64; o <<= 1) { su += __shfl_xor(su, o); si += __shfl_xor(si, o); }
    if ((threadIdx.x & 63) == 0) {
        atomicAdd(&accums[1], su);
        atomicAdd(&accums[2], si);
    }
}

// One wave per sample b: lane d handles feature d. diff = p_score - sum(n_scores).
__global__ void score_kernel(const int* __restrict__ x, const float* __restrict__ emb,
                             float* __restrict__ accums) {
    int wave = threadIdx.x >> 6;
    int lane = threadIdx.x & 63;
    int b = blockIdx.x * 4 + wave;
    const int* xb = x + b * 24;          // (B, S=6, 4) int32
    const float* ue = emb;
    const float* ie = emb + (size_t)N_USER_C * 64;
    int up = xb[0], ip = xb[1];
    float t = ue[(size_t)up * 64 + lane] * ie[(size_t)ip * 64 + lane];
    #pragma unroll
    for (int s = 1; s <= 4; ++s) {
        int un = xb[s * 4], in_ = xb[s * 4 + 1];
        t -= ue[(size_t)un * 64 + lane] * ie[(size_t)in_ * 64 + lane];
    }
    #pragma unroll
    for (int o = 1; o < 64; o <<= 1) t += __shfl_xor(t, o);
    if (lane == 0) {
        float sig = 1.0f / (1.0f + expf(-t));     // expf overflow -> sig=0, log(1e-10) ok
        float lossb = -logf(1e-10f + sig);
        atomicAdd(&accums[0], lossb);
    }
}

__global__ void final_kernel(const float* __restrict__ accums, float* __restrict__ out) {
    if (threadIdx.x == 0 && blockIdx.x == 0) {
        float bpr = accums[0] / 4096.0f;
        float emb_loss = (sqrtf(accums[1]) + sqrtf(accums[2])) / (float)N_ITEM_C;
        out[0] = bpr + 1e-4f * emb_loss;
    }
}

// ---- launch ---------------------------------------------------------------

extern "C" void kernel_launch(void* const* d_in, const int* in_sizes, int n_in,
                              void* d_out, int out_size, void* d_ws, size_t ws_size,
                              hipStream_t stream) {
    const int*   x    = (const int*)d_in[0];
    const float* uw   = (const float*)d_in[1];
    const float* iw   = (const float*)d_in[2];
    const int*   arow = (const int*)d_in[3];
    const int*   acol = (const int*)d_in[4];
    const float* aval = (const float*)d_in[5];
    int nnz = in_sizes[3];

    char* ws = (char*)d_ws;
    size_t off = 0;
    auto alloc = [&](size_t bytes) -> void* {
        void* p = ws + off;
        off += bytes;
        off = (off + 255) & ~(size_t)255;
        return p;
    };
    float* h_a     = (float*)alloc((size_t)ND_C * 4);
    float* h_b     = (float*)alloc((size_t)ND_C * 4);
    float* out_acc = (float*)alloc((size_t)ND_C * 4);
    int*   cnt     = (int*)alloc((size_t)NN_C * 4);
    int*   row_ptr = (int*)alloc((size_t)(NN_C + 1) * 4);
    int*   csr_col = (int*)alloc((size_t)nnz * 4);
    float* csr_val = (float*)alloc((size_t)nnz * 4);
    float* accums  = (float*)alloc(64);

    hipMemsetAsync(cnt, 0, (size_t)NN_C * 4, stream);
    hipMemsetAsync(accums, 0, 64, stream);

    const int eb = 256;
    int egrid = (nnz + eb - 1) / eb;
    if (egrid > 4096) egrid = 4096;

    count_kernel<<<egrid, eb, 0, stream>>>(arow, cnt, nnz);
    scan_kernel<<<1, 1024, 0, stream>>>(cnt, row_ptr, NN_C, nnz);
    hipMemsetAsync(cnt, 0, (size_t)NN_C * 4, stream);
    scatter_kernel<<<egrid, eb, 0, stream>>>(arow, acol, aval, row_ptr, cnt,
                                             csr_col, csr_val, nnz);

    init_kernel<<<2048, 256, 0, stream>>>((const float4*)uw, (const float4*)iw,
                                          (float4*)h_a, (float4*)out_acc,
                                          N_USER_C * D_C / 4, ND_C / 4);

    int sgrid = (NN_C * 16 + 255) / 256;   // 12500 blocks
    spmv_kernel<<<sgrid, 256, 0, stream>>>(h_a, h_b, out_acc, row_ptr, csr_col, csr_val, 2.0f);
    spmv_kernel<<<sgrid, 256, 0, stream>>>(h_b, h_a, out_acc, row_ptr, csr_col, csr_val, 1.5f);
    spmv_kernel<<<sgrid, 256, 0, stream>>>(h_a, h_b, out_acc, row_ptr, csr_col, csr_val, 4.0f / 3.0f);

    ssq_kernel<<<2048, 256, 0, stream>>>((const float4*)uw, (const float4*)iw,
                                         accums, N_USER_C * D_C / 4);
    score_kernel<<<1024, 256, 0, stream>>>(x, out_acc, accums);
    final_kernel<<<1, 64, 0, stream>>>(accums, (float*)d_out);
}

// Round 2
// 1101.280 us; speedup vs baseline: 1.3902x; 1.3902x over previous
//
#include <hip/hip_runtime.h>
#include <hip/hip_bf16.h>

#define N_USER_C 100000
#define N_ITEM_C 100000
#define D_C 64
#define NN_C (N_USER_C + N_ITEM_C)
#define ND_C (NN_C * D_C)   /* 12,800,000 floats */

#define SCAN_ITEMS 4
#define SCAN_BLOCK 256
#define SCAN_CHUNK (SCAN_BLOCK * SCAN_ITEMS)              /* 1024 */
#define SCAN_NBLK ((NN_C + SCAN_CHUNK - 1) / SCAN_CHUNK)  /* 196  */

// ---- CSR build ------------------------------------------------------------

__global__ void count_kernel(const int* __restrict__ row, int* __restrict__ cnt, int nnz) {
    int stride = gridDim.x * blockDim.x;
    for (int e = blockIdx.x * blockDim.x + threadIdx.x; e < nnz; e += stride)
        atomicAdd(&cnt[row[e]], 1);
}

// pass1: per-block totals of cnt chunks
__global__ void scan_pass1(const int* __restrict__ cnt, int* __restrict__ bsum, int n) {
    __shared__ int s[SCAN_BLOCK / 64];
    int b = blockIdx.x, t = threadIdx.x;
    int base = b * SCAN_CHUNK + t * SCAN_ITEMS;
    int sum = 0;
    #pragma unroll
    for (int i = 0; i < SCAN_ITEMS; ++i) {
        int idx = base + i;
        if (idx < n) sum += cnt[idx];
    }
    #pragma unroll
    for (int o = 1; o < 64; o <<= 1) sum += __shfl_xor(sum, o);
    if ((t & 63) == 0) s[t >> 6] = sum;
    __syncthreads();
    if (t == 0) {
        int tot = 0;
        #pragma unroll
        for (int w = 0; w < SCAN_BLOCK / 64; ++w) tot += s[w];
        bsum[b] = tot;
    }
}

// pass2: exclusive scan of the <=256 block sums, in place
__global__ void scan_pass2(int* __restrict__ bsum, int nb) {
    __shared__ int s[256];
    int t = threadIdx.x;
    s[t] = (t < nb) ? bsum[t] : 0;
    __syncthreads();
    for (int o = 1; o < 256; o <<= 1) {
        int v = (t >= o) ? s[t - o] : 0;
        __syncthreads();
        s[t] += v;
        __syncthreads();
    }
    if (t < nb) bsum[t] = (t == 0) ? 0 : s[t - 1];
}

// pass3: re-read chunk, local scan, add block offset, emit row_ptr
__global__ void scan_pass3(const int* __restrict__ cnt, const int* __restrict__ bsum,
                           int* __restrict__ row_ptr, int n, int nnz) {
    __shared__ int s[SCAN_BLOCK];
    int b = blockIdx.x, t = threadIdx.x;
    int base = b * SCAN_CHUNK + t * SCAN_ITEMS;
    int loc[SCAN_ITEMS];
    int sum = 0;
    #pragma unroll
    for (int i = 0; i < SCAN_ITEMS; ++i) {
        int idx = base + i;
        int v = (idx < n) ? cnt[idx] : 0;
        loc[i] = sum;
        sum += v;
    }
    s[t] = sum;
    __syncthreads();
    for (int o = 1; o < SCAN_BLOCK; o <<= 1) {
        int v = (t >= o) ? s[t - o] : 0;
        __syncthreads();
        s[t] += v;
        __syncthreads();
    }
    int texc = (t == 0) ? 0 : s[t - 1];
    int off = bsum[b] + texc;
    #pragma unroll
    for (int i = 0; i < SCAN_ITEMS; ++i) {
        int idx = base + i;
        if (idx < n) row_ptr[idx] = off + loc[i];
    }
    if (b == 0 && t == 0) row_ptr[n] = nnz;
}

__global__ void scatter_kernel(const int* __restrict__ row, const int* __restrict__ col,
                               const float* __restrict__ val, const int* __restrict__ row_ptr,
                               int* __restrict__ fill, int2* __restrict__ csr_cv, int nnz) {
    int stride = gridDim.x * blockDim.x;
    for (int e = blockIdx.x * blockDim.x + threadIdx.x; e < nnz; e += stride) {
        int r = row[e];
        int p = atomicAdd(&fill[r], 1);
        csr_cv[row_ptr[r] + p] = make_int2(col[e], __float_as_int(val[e]));
    }
}

// ---- propagation ----------------------------------------------------------
// One 16-lane group per row; lane l owns floats [4l,4l+4). 4-way unrolled
// gather (4 outstanding 256B loads/group), fused row-normalize via 16-lane
// shfl reduce. SPLIT: layer-1 reads directly from uw/iw (no h0 buffer).

template <bool SPLIT>
__global__ __launch_bounds__(256) void spmv_kernel(
        const float* __restrict__ hin, const float* __restrict__ uw,
        const float* __restrict__ iw, float* __restrict__ hout,
        const int* __restrict__ row_ptr, const int2* __restrict__ csr_cv) {
    int gid = blockIdx.x * blockDim.x + threadIdx.x;
    int r = gid >> 4;
    int l = gid & 15;
    if (r >= NN_C) return;
    int e0 = row_ptr[r], e1 = row_ptr[r + 1];

    auto src = [&](int c) -> const float* {
        if (SPLIT)
            return (c < N_USER_C) ? uw + (size_t)c * 64
                                  : iw + (size_t)(c - N_USER_C) * 64;
        else
            return hin + (size_t)c * 64;
    };

    float4 a0 = {0, 0, 0, 0}, a1 = {0, 0, 0, 0}, a2 = {0, 0, 0, 0}, a3 = {0, 0, 0, 0};
    int e = e0;
    for (; e + 4 <= e1; e += 4) {
        int2 c0 = csr_cv[e], c1 = csr_cv[e + 1], c2 = csr_cv[e + 2], c3 = csr_cv[e + 3];
        float4 h0 = *reinterpret_cast<const float4*>(src(c0.x) + l * 4);
        float4 h1 = *reinterpret_cast<const float4*>(src(c1.x) + l * 4);
        float4 h2 = *reinterpret_cast<const float4*>(src(c2.x) + l * 4);
        float4 h3 = *reinterpret_cast<const float4*>(src(c3.x) + l * 4);
        float v0 = __int_as_float(c0.y), v1 = __int_as_float(c1.y);
        float v2 = __int_as_float(c2.y), v3 = __int_as_float(c3.y);
        a0.x += v0 * h0.x; a0.y += v0 * h0.y; a0.z += v0 * h0.z; a0.w += v0 * h0.w;
        a1.x += v1 * h1.x; a1.y += v1 * h1.y; a1.z += v1 * h1.z; a1.w += v1 * h1.w;
        a2.x += v2 * h2.x; a2.y += v2 * h2.y; a2.z += v2 * h2.z; a2.w += v2 * h2.w;
        a3.x += v3 * h3.x; a3.y += v3 * h3.y; a3.z += v3 * h3.z; a3.w += v3 * h3.w;
    }
    for (; e < e1; ++e) {
        int2 c0 = csr_cv[e];
        float4 h0 = *reinterpret_cast<const float4*>(src(c0.x) + l * 4);
        float v0 = __int_as_float(c0.y);
        a0.x += v0 * h0.x; a0.y += v0 * h0.y; a0.z += v0 * h0.z; a0.w += v0 * h0.w;
    }
    float4 acc;
    acc.x = (a0.x + a1.x) + (a2.x + a3.x);
    acc.y = (a0.y + a1.y) + (a2.y + a3.y);
    acc.z = (a0.z + a1.z) + (a2.z + a3.z);
    acc.w = (a0.w + a1.w) + (a2.w + a3.w);

    float ss = acc.x * acc.x + acc.y * acc.y + acc.z * acc.z + acc.w * acc.w;
    ss += __shfl_xor(ss, 1);
    ss += __shfl_xor(ss, 2);
    ss += __shfl_xor(ss, 4);
    ss += __shfl_xor(ss, 8);
    float scale = 1.0f / fmaxf(sqrtf(ss), 1e-12f);
    float4 hn = make_float4(acc.x * scale, acc.y * scale, acc.z * scale, acc.w * scale);
    *reinterpret_cast<float4*>(hout + (size_t)r * 64 + l * 4) = hn;
}

// ---- losses ---------------------------------------------------------------

__global__ void ssq_kernel(const float4* __restrict__ uw, const float4* __restrict__ iw,
                           float* __restrict__ accums, int n4) {
    int stride = gridDim.x * blockDim.x;
    float su = 0.f, si = 0.f;
    int tot = 2 * n4;
    for (int i = blockIdx.x * blockDim.x + threadIdx.x; i < tot; i += stride) {
        float4 v = (i < n4) ? uw[i] : iw[i - n4];
        float d = v.x * v.x + v.y * v.y + v.z * v.z + v.w * v.w;
        if (i < n4) su += d; else si += d;
    }
    #pragma unroll
    for (int o = 1; o < 64; o <<= 1) { su += __shfl_xor(su, o); si += __shfl_xor(si, o); }
    if ((threadIdx.x & 63) == 0) {
        atomicAdd(&accums[1], su);
        atomicAdd(&accums[2], si);
    }
}

// One wave per sample: emb(r) = base(r) + 2*h1 + 1.5*h2 + (4/3)*h3, on the fly.
__global__ void score_kernel(const int* __restrict__ x,
                             const float* __restrict__ uw, const float* __restrict__ iw,
                             const float* __restrict__ h1, const float* __restrict__ h2,
                             const float* __restrict__ h3, float* __restrict__ accums) {
    int wave = threadIdx.x >> 6;
    int lane = threadIdx.x & 63;
    int b = blockIdx.x * 4 + wave;
    const int* xb = x + b * 24;          // (B, S=6, 4) int32

    auto emb = [&](int r) -> float {
        size_t o = (size_t)r * 64 + lane;
        float base = (r < N_USER_C) ? uw[o] : iw[o - (size_t)N_USER_C * 64];
        return base + 2.0f * h1[o] + 1.5f * h2[o] + (4.0f / 3.0f) * h3[o];
    };

    float t = emb(xb[0]) * emb(N_USER_C + xb[1]);
    #pragma unroll
    for (int s = 1; s <= 4; ++s)
        t -= emb(xb[s * 4]) * emb(N_USER_C + xb[s * 4 + 1]);

    #pragma unroll
    for (int o = 1; o < 64; o <<= 1) t += __shfl_xor(t, o);
    if (lane == 0) {
        float sig = 1.0f / (1.0f + expf(-t));
        atomicAdd(&accums[0], -logf(1e-10f + sig));
    }
}

__global__ void final_kernel(const float* __restrict__ accums, float* __restrict__ out) {
    if (threadIdx.x == 0 && blockIdx.x == 0) {
        float bpr = accums[0] / 4096.0f;
        float emb_loss = (sqrtf(accums[1]) + sqrtf(accums[2])) / (float)N_ITEM_C;
        out[0] = bpr + 1e-4f * emb_loss;
    }
}

// ---- launch ---------------------------------------------------------------

extern "C" void kernel_launch(void* const* d_in, const int* in_sizes, int n_in,
                              void* d_out, int out_size, void* d_ws, size_t ws_size,
                              hipStream_t stream) {
    const int*   x    = (const int*)d_in[0];
    const float* uw   = (const float*)d_in[1];
    const float* iw   = (const float*)d_in[2];
    const int*   arow = (const int*)d_in[3];
    const int*   acol = (const int*)d_in[4];
    const float* aval = (const float*)d_in[5];
    int nnz = in_sizes[3];

    char* ws = (char*)d_ws;
    size_t off = 0;
    auto alloc = [&](size_t bytes) -> void* {
        void* p = ws + off;
        off += bytes;
        off = (off + 255) & ~(size_t)255;
        return p;
    };
    float* h1      = (float*)alloc((size_t)ND_C * 4);
    float* h2      = (float*)alloc((size_t)ND_C * 4);
    float* h3      = (float*)alloc((size_t)ND_C * 4);
    int2*  csr_cv  = (int2*)alloc((size_t)nnz * 8);
    int*   cnt     = (int*)alloc((size_t)NN_C * 4);
    int*   row_ptr = (int*)alloc((size_t)(NN_C + 1) * 4);
    int*   bsum    = (int*)alloc((size_t)256 * 4);
    float* accums  = (float*)alloc(64);

    hipMemsetAsync(cnt, 0, (size_t)NN_C * 4, stream);
    hipMemsetAsync(accums, 0, 64, stream);

    const int eb = 256;
    int egrid = (nnz + eb - 1) / eb;
    if (egrid > 4096) egrid = 4096;

    count_kernel<<<egrid, eb, 0, stream>>>(arow, cnt, nnz);
    scan_pass1<<<SCAN_NBLK, SCAN_BLOCK, 0, stream>>>(cnt, bsum, NN_C);
    scan_pass2<<<1, 256, 0, stream>>>(bsum, SCAN_NBLK);
    scan_pass3<<<SCAN_NBLK, SCAN_BLOCK, 0, stream>>>(cnt, bsum, row_ptr, NN_C, nnz);
    hipMemsetAsync(cnt, 0, (size_t)NN_C * 4, stream);
    scatter_kernel<<<egrid, eb, 0, stream>>>(arow, acol, aval, row_ptr, cnt, csr_cv, nnz);

    int sgrid = (NN_C * 16 + 255) / 256;   // 12500 blocks
    spmv_kernel<true><<<sgrid, 256, 0, stream>>>(nullptr, uw, iw, h1, row_ptr, csr_cv);
    spmv_kernel<false><<<sgrid, 256, 0, stream>>>(h1, uw, iw, h2, row_ptr, csr_cv);
    spmv_kernel<false><<<sgrid, 256, 0, stream>>>(h2, uw, iw, h3, row_ptr, csr_cv);

    ssq_kernel<<<2048, 256, 0, stream>>>((const float4*)uw, (const float4*)iw,
                                         accums, N_USER_C * D_C / 4);
    score_kernel<<<1024, 256, 0, stream>>>(x, uw, iw, h1, h2, h3, accums);
    final_kernel<<<1, 64, 0, stream>>>(accums, (float*)d_out);
}

// Round 3
// 886.581 us; speedup vs baseline: 1.7269x; 1.2422x over previous
//
#include <hip/hip_runtime.h>
#include <hip/hip_bf16.h>

#define N_USER_C 100000
#define N_ITEM_C 100000
#define D_C 64
#define NN_C (N_USER_C + N_ITEM_C)
#define ND_C (NN_C * D_C)   /* 12,800,000 floats */

#define SCAN_ITEMS 4
#define SCAN_BLOCK 256
#define SCAN_CHUNK (SCAN_BLOCK * SCAN_ITEMS)                  /* 1024 */
#define SCAN_NBLK_I ((N_ITEM_C + SCAN_CHUNK - 1) / SCAN_CHUNK) /* 98 */

// ---- CSR build (item half only; user half is already CSR-ordered) ---------

__global__ void item_count_kernel(const int* __restrict__ arow, int* __restrict__ cnt,
                                  int ne) {
    int stride = gridDim.x * blockDim.x;
    for (int e = blockIdx.x * blockDim.x + threadIdx.x; e < ne; e += stride)
        atomicAdd(&cnt[arow[ne + e] - N_USER_C], 1);
}

__global__ void scan_pass1(const int* __restrict__ cnt, int* __restrict__ bsum, int n) {
    __shared__ int s[SCAN_BLOCK / 64];
    int b = blockIdx.x, t = threadIdx.x;
    int base = b * SCAN_CHUNK + t * SCAN_ITEMS;
    int sum = 0;
    #pragma unroll
    for (int i = 0; i < SCAN_ITEMS; ++i) {
        int idx = base + i;
        if (idx < n) sum += cnt[idx];
    }
    #pragma unroll
    for (int o = 1; o < 64; o <<= 1) sum += __shfl_xor(sum, o);
    if ((t & 63) == 0) s[t >> 6] = sum;
    __syncthreads();
    if (t == 0) {
        int tot = 0;
        #pragma unroll
        for (int w = 0; w < SCAN_BLOCK / 64; ++w) tot += s[w];
        bsum[b] = tot;
    }
}

__global__ void scan_pass2(int* __restrict__ bsum, int nb) {
    __shared__ int s[256];
    int t = threadIdx.x;
    s[t] = (t < nb) ? bsum[t] : 0;
    __syncthreads();
    for (int o = 1; o < 256; o <<= 1) {
        int v = (t >= o) ? s[t - o] : 0;
        __syncthreads();
        s[t] += v;
        __syncthreads();
    }
    if (t < nb) bsum[t] = (t == 0) ? 0 : s[t - 1];
}

__global__ void scan_pass3(const int* __restrict__ cnt, const int* __restrict__ bsum,
                           int* __restrict__ row_ptr, int n, int nnz) {
    __shared__ int s[SCAN_BLOCK];
    int b = blockIdx.x, t = threadIdx.x;
    int base = b * SCAN_CHUNK + t * SCAN_ITEMS;
    int loc[SCAN_ITEMS];
    int sum = 0;
    #pragma unroll
    for (int i = 0; i < SCAN_ITEMS; ++i) {
        int idx = base + i;
        int v = (idx < n) ? cnt[idx] : 0;
        loc[i] = sum;
        sum += v;
    }
    s[t] = sum;
    __syncthreads();
    for (int o = 1; o < SCAN_BLOCK; o <<= 1) {
        int v = (t >= o) ? s[t - o] : 0;
        __syncthreads();
        s[t] += v;
        __syncthreads();
    }
    int texc = (t == 0) ? 0 : s[t - 1];
    int off = bsum[b] + texc;
    #pragma unroll
    for (int i = 0; i < SCAN_ITEMS; ++i) {
        int idx = base + i;
        if (idx < n) row_ptr[idx] = off + loc[i];
    }
    if (b == 0 && t == 0) row_ptr[n] = nnz;
}

// arow[0:ne] is sorted ascending (user ids). row_ptr_u[r] = first e with arow[e] >= r.
__global__ void user_rowptr_kernel(const int* __restrict__ arow, int* __restrict__ row_ptr_u,
                                   int ne) {
    int stride = gridDim.x * blockDim.x;
    for (int e = blockIdx.x * blockDim.x + threadIdx.x; e <= ne; e += stride) {
        int prev = (e == 0) ? -1 : arow[e - 1];
        int cur = (e == ne) ? N_USER_C : arow[e];
        for (int r = prev + 1; r <= cur; ++r) row_ptr_u[r] = e;
    }
}

__global__ void item_scatter_kernel(const int* __restrict__ arow, const int* __restrict__ acol,
                                    const float* __restrict__ aval,
                                    const int* __restrict__ row_ptr_i,
                                    int* __restrict__ fill, int2* __restrict__ csr_cv, int ne) {
    int stride = gridDim.x * blockDim.x;
    for (int e = blockIdx.x * blockDim.x + threadIdx.x; e < ne; e += stride) {
        int ge = ne + e;
        int j = arow[ge] - N_USER_C;
        int p = atomicAdd(&fill[j], 1);
        csr_cv[row_ptr_i[j] + p] = make_int2(acol[ge], __float_as_int(aval[ge]));
    }
}

// ---- propagation ----------------------------------------------------------
// One 16-lane group per row; lane l owns floats [4l,4l+4).
// USER_ROWS: rows 0..N_USER, edges directly from (acol,aval), cols are item ids
//            (>= N_USER); gather from iw (SPLIT) or hin+c*64.
// !USER_ROWS: rows N_USER..NN, edges from csr_cv, cols are user ids (< N_USER);
//            gather from uw (SPLIT) or hin+c*64.

template <bool SPLIT, bool USER_ROWS>
__global__ __launch_bounds__(256) void spmv_kernel(
        const float* __restrict__ hin, const float* __restrict__ uw,
        const float* __restrict__ iw, float* __restrict__ hout,
        const int* __restrict__ row_ptr, const int* __restrict__ acol,
        const float* __restrict__ aval, const int2* __restrict__ csr_cv) {
    int gid = blockIdx.x * blockDim.x + threadIdx.x;
    int rr = gid >> 4;                         // local row within half
    int l = gid & 15;
    int nrows = USER_ROWS ? N_USER_C : N_ITEM_C;
    if (rr >= nrows) return;
    int e0 = row_ptr[rr], e1 = row_ptr[rr + 1];

    auto src = [&](int c) -> const float* {
        if (USER_ROWS) {  // c is a global item col id (>= N_USER)
            if (SPLIT) return iw + (size_t)(c - N_USER_C) * 64;
            return hin + (size_t)c * 64;
        } else {          // c is a user id (< N_USER)
            if (SPLIT) return uw + (size_t)c * 64;
            return hin + (size_t)c * 64;
        }
    };
    auto edge = [&](int e, int& c, float& v) {
        if (USER_ROWS) { c = acol[e]; v = aval[e]; }
        else { int2 cv = csr_cv[e]; c = cv.x; v = __int_as_float(cv.y); }
    };

    float4 a0 = {0, 0, 0, 0}, a1 = {0, 0, 0, 0}, a2 = {0, 0, 0, 0}, a3 = {0, 0, 0, 0};
    int e = e0;
    for (; e + 4 <= e1; e += 4) {
        int c0, c1, c2, c3; float v0, v1, v2, v3;
        edge(e, c0, v0); edge(e + 1, c1, v1); edge(e + 2, c2, v2); edge(e + 3, c3, v3);
        float4 h0 = *reinterpret_cast<const float4*>(src(c0) + l * 4);
        float4 h1 = *reinterpret_cast<const float4*>(src(c1) + l * 4);
        float4 h2 = *reinterpret_cast<const float4*>(src(c2) + l * 4);
        float4 h3 = *reinterpret_cast<const float4*>(src(c3) + l * 4);
        a0.x += v0 * h0.x; a0.y += v0 * h0.y; a0.z += v0 * h0.z; a0.w += v0 * h0.w;
        a1.x += v1 * h1.x; a1.y += v1 * h1.y; a1.z += v1 * h1.z; a1.w += v1 * h1.w;
        a2.x += v2 * h2.x; a2.y += v2 * h2.y; a2.z += v2 * h2.z; a2.w += v2 * h2.w;
        a3.x += v3 * h3.x; a3.y += v3 * h3.y; a3.z += v3 * h3.z; a3.w += v3 * h3.w;
    }
    for (; e < e1; ++e) {
        int c0; float v0;
        edge(e, c0, v0);
        float4 h0 = *reinterpret_cast<const float4*>(src(c0) + l * 4);
        a0.x += v0 * h0.x; a0.y += v0 * h0.y; a0.z += v0 * h0.z; a0.w += v0 * h0.w;
    }
    float4 acc;
    acc.x = (a0.x + a1.x) + (a2.x + a3.x);
    acc.y = (a0.y + a1.y) + (a2.y + a3.y);
    acc.z = (a0.z + a1.z) + (a2.z + a3.z);
    acc.w = (a0.w + a1.w) + (a2.w + a3.w);

    float ss = acc.x * acc.x + acc.y * acc.y + acc.z * acc.z + acc.w * acc.w;
    ss += __shfl_xor(ss, 1);
    ss += __shfl_xor(ss, 2);
    ss += __shfl_xor(ss, 4);
    ss += __shfl_xor(ss, 8);
    float scale = 1.0f / fmaxf(sqrtf(ss), 1e-12f);
    float4 hn = make_float4(acc.x * scale, acc.y * scale, acc.z * scale, acc.w * scale);
    size_t r = USER_ROWS ? rr : (N_USER_C + rr);
    *reinterpret_cast<float4*>(hout + r * 64 + l * 4) = hn;
}

// ---- losses ---------------------------------------------------------------

__global__ void ssq_kernel(const float4* __restrict__ uw, const float4* __restrict__ iw,
                           float* __restrict__ accums, int n4) {
    int stride = gridDim.x * blockDim.x;
    float su = 0.f, si = 0.f;
    int tot = 2 * n4;
    for (int i = blockIdx.x * blockDim.x + threadIdx.x; i < tot; i += stride) {
        float4 v = (i < n4) ? uw[i] : iw[i - n4];
        float d = v.x * v.x + v.y * v.y + v.z * v.z + v.w * v.w;
        if (i < n4) su += d; else si += d;
    }
    #pragma unroll
    for (int o = 1; o < 64; o <<= 1) { su += __shfl_xor(su, o); si += __shfl_xor(si, o); }
    if ((threadIdx.x & 63) == 0) {
        atomicAdd(&accums[1], su);
        atomicAdd(&accums[2], si);
    }
}

__global__ void score_kernel(const int* __restrict__ x,
                             const float* __restrict__ uw, const float* __restrict__ iw,
                             const float* __restrict__ h1, const float* __restrict__ h2,
                             const float* __restrict__ h3, float* __restrict__ accums) {
    int wave = threadIdx.x >> 6;
    int lane = threadIdx.x & 63;
    int b = blockIdx.x * 4 + wave;
    const int* xb = x + b * 24;          // (B, S=6, 4) int32

    auto emb = [&](int r) -> float {
        size_t o = (size_t)r * 64 + lane;
        float base = (r < N_USER_C) ? uw[o] : iw[o - (size_t)N_USER_C * 64];
        return base + 2.0f * h1[o] + 1.5f * h2[o] + (4.0f / 3.0f) * h3[o];
    };

    float t = emb(xb[0]) * emb(N_USER_C + xb[1]);
    #pragma unroll
    for (int s = 1; s <= 4; ++s)
        t -= emb(xb[s * 4]) * emb(N_USER_C + xb[s * 4 + 1]);

    #pragma unroll
    for (int o = 1; o < 64; o <<= 1) t += __shfl_xor(t, o);
    if (lane == 0) {
        float sig = 1.0f / (1.0f + expf(-t));
        atomicAdd(&accums[0], -logf(1e-10f + sig));
    }
}

__global__ void final_kernel(const float* __restrict__ accums, float* __restrict__ out) {
    if (threadIdx.x == 0 && blockIdx.x == 0) {
        float bpr = accums[0] / 4096.0f;
        float emb_loss = (sqrtf(accums[1]) + sqrtf(accums[2])) / (float)N_ITEM_C;
        out[0] = bpr + 1e-4f * emb_loss;
    }
}

// ---- launch ---------------------------------------------------------------

extern "C" void kernel_launch(void* const* d_in, const int* in_sizes, int n_in,
                              void* d_out, int out_size, void* d_ws, size_t ws_size,
                              hipStream_t stream) {
    const int*   x    = (const int*)d_in[0];
    const float* uw   = (const float*)d_in[1];
    const float* iw   = (const float*)d_in[2];
    const int*   arow = (const int*)d_in[3];
    const int*   acol = (const int*)d_in[4];
    const float* aval = (const float*)d_in[5];
    int nnz = in_sizes[3];
    int ne = nnz / 2;                     // edges per half

    char* ws = (char*)d_ws;
    size_t off = 0;
    auto alloc = [&](size_t bytes) -> void* {
        void* p = ws + off;
        off += bytes;
        off = (off + 255) & ~(size_t)255;
        return p;
    };
    float* h1        = (float*)alloc((size_t)ND_C * 4);
    float* h2        = (float*)alloc((size_t)ND_C * 4);
    float* h3        = (float*)alloc((size_t)ND_C * 4);
    int2*  csr_cv    = (int2*)alloc((size_t)ne * 8);
    int*   cnt       = (int*)alloc((size_t)N_ITEM_C * 4);
    int*   fill      = (int*)alloc((size_t)N_ITEM_C * 4);
    int*   row_ptr_u = (int*)alloc((size_t)(N_USER_C + 1) * 4);
    int*   row_ptr_i = (int*)alloc((size_t)(N_ITEM_C + 1) * 4);
    int*   bsum      = (int*)alloc((size_t)256 * 4);
    float* accums    = (float*)alloc(64);

    hipMemsetAsync(cnt, 0, (size_t)N_ITEM_C * 4, stream);
    hipMemsetAsync(fill, 0, (size_t)N_ITEM_C * 4, stream);
    hipMemsetAsync(accums, 0, 64, stream);

    const int eb = 256;
    int egrid = (ne + eb - 1) / eb;
    if (egrid > 4096) egrid = 4096;

    item_count_kernel<<<egrid, eb, 0, stream>>>(arow, cnt, ne);
    scan_pass1<<<SCAN_NBLK_I, SCAN_BLOCK, 0, stream>>>(cnt, bsum, N_ITEM_C);
    scan_pass2<<<1, 256, 0, stream>>>(bsum, SCAN_NBLK_I);
    scan_pass3<<<SCAN_NBLK_I, SCAN_BLOCK, 0, stream>>>(cnt, bsum, row_ptr_i, N_ITEM_C, ne);
    user_rowptr_kernel<<<egrid, eb, 0, stream>>>(arow, row_ptr_u, ne);
    item_scatter_kernel<<<egrid, eb, 0, stream>>>(arow, acol, aval, row_ptr_i, fill,
                                                  csr_cv, ne);

    int ugrid = (N_USER_C * 16 + 255) / 256;   // 6250
    int igrid = (N_ITEM_C * 16 + 255) / 256;
    // layer 1 (reads raw weights)
    spmv_kernel<true, true><<<ugrid, 256, 0, stream>>>(nullptr, uw, iw, h1,
                                                       row_ptr_u, acol, aval, csr_cv);
    spmv_kernel<true, false><<<igrid, 256, 0, stream>>>(nullptr, uw, iw, h1,
                                                        row_ptr_i, acol, aval, csr_cv);
    // layer 2
    spmv_kernel<false, true><<<ugrid, 256, 0, stream>>>(h1, uw, iw, h2,
                                                        row_ptr_u, acol, aval, csr_cv);
    spmv_kernel<false, false><<<igrid, 256, 0, stream>>>(h1, uw, iw, h2,
                                                         row_ptr_i, acol, aval, csr_cv);
    // layer 3
    spmv_kernel<false, true><<<ugrid, 256, 0, stream>>>(h2, uw, iw, h3,
                                                        row_ptr_u, acol, aval, csr_cv);
    spmv_kernel<false, false><<<igrid, 256, 0, stream>>>(h2, uw, iw, h3,
                                                         row_ptr_i, acol, aval, csr_cv);

    ssq_kernel<<<2048, 256, 0, stream>>>((const float4*)uw, (const float4*)iw,
                                         accums, N_USER_C * D_C / 4);
    score_kernel<<<1024, 256, 0, stream>>>(x, uw, iw, h1, h2, h3, accums);
    final_kernel<<<1, 64, 0, stream>>>(accums, (float*)d_out);
}

// Round 5
// 638.739 us; speedup vs baseline: 2.3969x; 1.3880x over previous
//
#include <hip/hip_runtime.h>
#include <hip/hip_bf16.h>

#define N_USER_C 100000
#define N_ITEM_C 100000
#define D_C 64
#define NN_C (N_USER_C + N_ITEM_C)
#define ND_C (NN_C * D_C)   /* 12,800,000 floats */

#define SCAN_ITEMS 4
#define SCAN_BLOCK 256
#define SCAN_CHUNK (SCAN_BLOCK * SCAN_ITEMS)                  /* 1024 */
#define SCAN_NBLK_I ((N_ITEM_C + SCAN_CHUNK - 1) / SCAN_CHUNK) /* 98 */

#define SSQ_NBLK 256
#define SCORE_NBLK 1024

// ---- CSR build (item half only; user half is already CSR-ordered) ---------

__global__ void item_count_kernel(const int* __restrict__ arow, int* __restrict__ cnt,
                                  int ne) {
    int stride = gridDim.x * blockDim.x;
    for (int e = blockIdx.x * blockDim.x + threadIdx.x; e < ne; e += stride)
        atomicAdd(&cnt[arow[ne + e] - N_USER_C], 1);
}

__global__ void scan_pass1(const int* __restrict__ cnt, int* __restrict__ bsum, int n) {
    __shared__ int s[SCAN_BLOCK / 64];
    int b = blockIdx.x, t = threadIdx.x;
    int base = b * SCAN_CHUNK + t * SCAN_ITEMS;
    int sum = 0;
    #pragma unroll
    for (int i = 0; i < SCAN_ITEMS; ++i) {
        int idx = base + i;
        if (idx < n) sum += cnt[idx];
    }
    #pragma unroll
    for (int o = 1; o < 64; o <<= 1) sum += __shfl_xor(sum, o);
    if ((t & 63) == 0) s[t >> 6] = sum;
    __syncthreads();
    if (t == 0) {
        int tot = 0;
        #pragma unroll
        for (int w = 0; w < SCAN_BLOCK / 64; ++w) tot += s[w];
        bsum[b] = tot;
    }
}

__global__ void scan_pass2(int* __restrict__ bsum, int nb) {
    __shared__ int s[256];
    int t = threadIdx.x;
    s[t] = (t < nb) ? bsum[t] : 0;
    __syncthreads();
    for (int o = 1; o < 256; o <<= 1) {
        int v = (t >= o) ? s[t - o] : 0;
        __syncthreads();
        s[t] += v;
        __syncthreads();
    }
    if (t < nb) bsum[t] = (t == 0) ? 0 : s[t - 1];
}

__global__ void scan_pass3(const int* __restrict__ cnt, const int* __restrict__ bsum,
                           int* __restrict__ row_ptr, int n, int nnz) {
    __shared__ int s[SCAN_BLOCK];
    int b = blockIdx.x, t = threadIdx.x;
    int base = b * SCAN_CHUNK + t * SCAN_ITEMS;
    int loc[SCAN_ITEMS];
    int sum = 0;
    #pragma unroll
    for (int i = 0; i < SCAN_ITEMS; ++i) {
        int idx = base + i;
        int v = (idx < n) ? cnt[idx] : 0;
        loc[i] = sum;
        sum += v;
    }
    s[t] = sum;
    __syncthreads();
    for (int o = 1; o < SCAN_BLOCK; o <<= 1) {
        int v = (t >= o) ? s[t - o] : 0;
        __syncthreads();
        s[t] += v;
        __syncthreads();
    }
    int texc = (t == 0) ? 0 : s[t - 1];
    int off = bsum[b] + texc;
    #pragma unroll
    for (int i = 0; i < SCAN_ITEMS; ++i) {
        int idx = base + i;
        if (idx < n) row_ptr[idx] = off + loc[i];
    }
    if (b == 0 && t == 0) row_ptr[n] = nnz;
}

// arow[0:ne] is sorted ascending (user ids). row_ptr_u[r] = first e with arow[e] >= r.
__global__ void user_rowptr_kernel(const int* __restrict__ arow, int* __restrict__ row_ptr_u,
                                   int ne) {
    int stride = gridDim.x * blockDim.x;
    for (int e = blockIdx.x * blockDim.x + threadIdx.x; e <= ne; e += stride) {
        int prev = (e == 0) ? -1 : arow[e - 1];
        int cur = (e == ne) ? N_USER_C : arow[e];
        for (int r = prev + 1; r <= cur; ++r) row_ptr_u[r] = e;
    }
}

__global__ void item_scatter_kernel(const int* __restrict__ arow, const int* __restrict__ acol,
                                    const float* __restrict__ aval,
                                    const int* __restrict__ row_ptr_i,
                                    int* __restrict__ fill, int2* __restrict__ csr_cv, int ne) {
    int stride = gridDim.x * blockDim.x;
    for (int e = blockIdx.x * blockDim.x + threadIdx.x; e < ne; e += stride) {
        int ge = ne + e;
        int j = arow[ge] - N_USER_C;
        int p = atomicAdd(&fill[j], 1);
        csr_cv[row_ptr_i[j] + p] = make_int2(acol[ge], __float_as_int(aval[ge]));
    }
}

// ---- propagation ----------------------------------------------------------

template <bool SPLIT, bool USER_ROWS>
__global__ __launch_bounds__(256) void spmv_kernel(
        const float* __restrict__ hin, const float* __restrict__ uw,
        const float* __restrict__ iw, float* __restrict__ hout,
        const int* __restrict__ row_ptr, const int* __restrict__ acol,
        const float* __restrict__ aval, const int2* __restrict__ csr_cv) {
    int gid = blockIdx.x * blockDim.x + threadIdx.x;
    int rr = gid >> 4;                         // local row within half
    int l = gid & 15;
    int nrows = USER_ROWS ? N_USER_C : N_ITEM_C;
    if (rr >= nrows) return;
    int e0 = row_ptr[rr], e1 = row_ptr[rr + 1];

    auto src = [&](int c) -> const float* {
        if (USER_ROWS) {  // c is a global item col id (>= N_USER)
            if (SPLIT) return iw + (size_t)(c - N_USER_C) * 64;
            return hin + (size_t)c * 64;
        } else {          // c is a user id (< N_USER)
            if (SPLIT) return uw + (size_t)c * 64;
            return hin + (size_t)c * 64;
        }
    };
    auto edge = [&](int e, int& c, float& v) {
        if (USER_ROWS) { c = acol[e]; v = aval[e]; }
        else { int2 cv = csr_cv[e]; c = cv.x; v = __int_as_float(cv.y); }
    };

    float4 a0 = {0, 0, 0, 0}, a1 = {0, 0, 0, 0}, a2 = {0, 0, 0, 0}, a3 = {0, 0, 0, 0};
    int e = e0;
    for (; e + 4 <= e1; e += 4) {
        int c0, c1, c2, c3; float v0, v1, v2, v3;
        edge(e, c0, v0); edge(e + 1, c1, v1); edge(e + 2, c2, v2); edge(e + 3, c3, v3);
        float4 h0 = *reinterpret_cast<const float4*>(src(c0) + l * 4);
        float4 h1 = *reinterpret_cast<const float4*>(src(c1) + l * 4);
        float4 h2 = *reinterpret_cast<const float4*>(src(c2) + l * 4);
        float4 h3 = *reinterpret_cast<const float4*>(src(c3) + l * 4);
        a0.x += v0 * h0.x; a0.y += v0 * h0.y; a0.z += v0 * h0.z; a0.w += v0 * h0.w;
        a1.x += v1 * h1.x; a1.y += v1 * h1.y; a1.z += v1 * h1.z; a1.w += v1 * h1.w;
        a2.x += v2 * h2.x; a2.y += v2 * h2.y; a2.z += v2 * h2.z; a2.w += v2 * h2.w;
        a3.x += v3 * h3.x; a3.y += v3 * h3.y; a3.z += v3 * h3.z; a3.w += v3 * h3.w;
    }
    for (; e < e1; ++e) {
        int c0; float v0;
        edge(e, c0, v0);
        float4 h0 = *reinterpret_cast<const float4*>(src(c0) + l * 4);
        a0.x += v0 * h0.x; a0.y += v0 * h0.y; a0.z += v0 * h0.z; a0.w += v0 * h0.w;
    }
    float4 acc;
    acc.x = (a0.x + a1.x) + (a2.x + a3.x);
    acc.y = (a0.y + a1.y) + (a2.y + a3.y);
    acc.z = (a0.z + a1.z) + (a2.z + a3.z);
    acc.w = (a0.w + a1.w) + (a2.w + a3.w);

    float ss = acc.x * acc.x + acc.y * acc.y + acc.z * acc.z + acc.w * acc.w;
    ss += __shfl_xor(ss, 1);
    ss += __shfl_xor(ss, 2);
    ss += __shfl_xor(ss, 4);
    ss += __shfl_xor(ss, 8);
    float scale = 1.0f / fmaxf(sqrtf(ss), 1e-12f);
    float4 hn = make_float4(acc.x * scale, acc.y * scale, acc.z * scale, acc.w * scale);
    size_t r = USER_ROWS ? rr : (N_USER_C + rr);
    *reinterpret_cast<float4*>(hout + r * 64 + l * 4) = hn;
}

// ---- losses (two-stage, atomic-free) ---------------------------------------

__global__ void ssq_kernel(const float4* __restrict__ uw, const float4* __restrict__ iw,
                           float2* __restrict__ partial_sq, int n4) {
    __shared__ float s_u[4], s_i[4];
    int stride = gridDim.x * blockDim.x;
    float su = 0.f, si = 0.f;
    int tot = 2 * n4;
    for (int i = blockIdx.x * blockDim.x + threadIdx.x; i < tot; i += stride) {
        float4 v = (i < n4) ? uw[i] : iw[i - n4];
        float d = v.x * v.x + v.y * v.y + v.z * v.z + v.w * v.w;
        if (i < n4) su += d; else si += d;
    }
    #pragma unroll
    for (int o = 1; o < 64; o <<= 1) { su += __shfl_xor(su, o); si += __shfl_xor(si, o); }
    int w = threadIdx.x >> 6;
    if ((threadIdx.x & 63) == 0) { s_u[w] = su; s_i[w] = si; }
    __syncthreads();
    if (threadIdx.x == 0) {
        float tu = s_u[0] + s_u[1] + s_u[2] + s_u[3];
        float ti = s_i[0] + s_i[1] + s_i[2] + s_i[3];
        partial_sq[blockIdx.x] = make_float2(tu, ti);
    }
}

// One wave per sample: emb(r) = base(r) + 2*h1 + 1.5*h2 + (4/3)*h3, on the fly.
// Per-block (4 samples) partial loss, plain store — no atomics.
__global__ void score_kernel(const int* __restrict__ x,
                             const float* __restrict__ uw, const float* __restrict__ iw,
                             const float* __restrict__ h1, const float* __restrict__ h2,
                             const float* __restrict__ h3, float* __restrict__ partial_loss) {
    __shared__ float s_l[4];
    int wave = threadIdx.x >> 6;
    int lane = threadIdx.x & 63;
    int b = blockIdx.x * 4 + wave;
    const int* xb = x + b * 24;          // (B, S=6, 4) int32

    auto emb = [&](int r) -> float {
        size_t o = (size_t)r * 64 + lane;
        float base = (r < N_USER_C) ? uw[o] : iw[o - (size_t)N_USER_C * 64];
        return base + 2.0f * h1[o] + 1.5f * h2[o] + (4.0f / 3.0f) * h3[o];
    };

    float t = emb(xb[0]) * emb(N_USER_C + xb[1]);
    #pragma unroll
    for (int s = 1; s <= 4; ++s)
        t -= emb(xb[s * 4]) * emb(N_USER_C + xb[s * 4 + 1]);

    #pragma unroll
    for (int o = 1; o < 64; o <<= 1) t += __shfl_xor(t, o);
    if (lane == 0) {
        float sig = 1.0f / (1.0f + expf(-t));
        s_l[wave] = -logf(1e-10f + sig);
    }
    __syncthreads();
    if (threadIdx.x == 0)
        partial_loss[blockIdx.x] = s_l[0] + s_l[1] + s_l[2] + s_l[3];
}

__global__ void final_kernel(const float2* __restrict__ partial_sq,
                             const float* __restrict__ partial_loss,
                             float* __restrict__ out) {
    __shared__ float s_u[4], s_i[4], s_l[4];
    int t = threadIdx.x;
    int w = t >> 6, lane = t & 63;

    float2 p = partial_sq[t];            // SSQ_NBLK == 256 == blockDim
    float su = p.x, si = p.y;
    float lo = 0.f;
    #pragma unroll
    for (int k = 0; k < SCORE_NBLK / 256; ++k) lo += partial_loss[t + k * 256];

    #pragma unroll
    for (int o = 1; o < 64; o <<= 1) {
        su += __shfl_xor(su, o);
        si += __shfl_xor(si, o);
        lo += __shfl_xor(lo, o);
    }
    if (lane == 0) { s_u[w] = su; s_i[w] = si; s_l[w] = lo; }
    __syncthreads();
    if (t == 0) {
        float tu = s_u[0] + s_u[1] + s_u[2] + s_u[3];
        float ti = s_i[0] + s_i[1] + s_i[2] + s_i[3];
        float tl = s_l[0] + s_l[1] + s_l[2] + s_l[3];
        float bpr = tl / 4096.0f;
        float emb_loss = (sqrtf(tu) + sqrtf(ti)) / (float)N_ITEM_C;
        out[0] = bpr + 1e-4f * emb_loss;
    }
}

// ---- launch ---------------------------------------------------------------

extern "C" void kernel_launch(void* const* d_in, const int* in_sizes, int n_in,
                              void* d_out, int out_size, void* d_ws, size_t ws_size,
                              hipStream_t stream) {
    const int*   x    = (const int*)d_in[0];
    const float* uw   = (const float*)d_in[1];
    const float* iw   = (const float*)d_in[2];
    const int*   arow = (const int*)d_in[3];
    const int*   acol = (const int*)d_in[4];
    const float* aval = (const float*)d_in[5];
    int nnz = in_sizes[3];
    int ne = nnz / 2;                     // edges per half

    char* ws = (char*)d_ws;
    size_t off = 0;
    auto alloc = [&](size_t bytes) -> void* {
        void* p = ws + off;
        off += bytes;
        off = (off + 255) & ~(size_t)255;
        return p;
    };
    float*  h1        = (float*)alloc((size_t)ND_C * 4);
    float*  h2        = (float*)alloc((size_t)ND_C * 4);
    float*  h3        = (float*)alloc((size_t)ND_C * 4);
    int2*   csr_cv    = (int2*)alloc((size_t)ne * 8);
    int*    cnt       = (int*)alloc((size_t)N_ITEM_C * 4);
    int*    fill      = (int*)alloc((size_t)N_ITEM_C * 4);
    int*    row_ptr_u = (int*)alloc((size_t)(N_USER_C + 1) * 4);
    int*    row_ptr_i = (int*)alloc((size_t)(N_ITEM_C + 1) * 4);
    int*    bsum      = (int*)alloc((size_t)256 * 4);
    float2* psq       = (float2*)alloc((size_t)SSQ_NBLK * 8);
    float*  ploss     = (float*)alloc((size_t)SCORE_NBLK * 4);

    hipMemsetAsync(cnt, 0, (size_t)N_ITEM_C * 4, stream);
    hipMemsetAsync(fill, 0, (size_t)N_ITEM_C * 4, stream);

    const int eb = 256;
    int egrid = (ne + eb - 1) / eb;
    if (egrid > 4096) egrid = 4096;

    item_count_kernel<<<egrid, eb, 0, stream>>>(arow, cnt, ne);
    scan_pass1<<<SCAN_NBLK_I, SCAN_BLOCK, 0, stream>>>(cnt, bsum, N_ITEM_C);
    scan_pass2<<<1, 256, 0, stream>>>(bsum, SCAN_NBLK_I);
    scan_pass3<<<SCAN_NBLK_I, SCAN_BLOCK, 0, stream>>>(cnt, bsum, row_ptr_i, N_ITEM_C, ne);
    user_rowptr_kernel<<<egrid, eb, 0, stream>>>(arow, row_ptr_u, ne);
    item_scatter_kernel<<<egrid, eb, 0, stream>>>(arow, acol, aval, row_ptr_i, fill,
                                                  csr_cv, ne);

    int ugrid = (N_USER_C * 16 + 255) / 256;   // 6250
    int igrid = (N_ITEM_C * 16 + 255) / 256;
    // layer 1 (reads raw weights)
    spmv_kernel<true, true><<<ugrid, 256, 0, stream>>>(nullptr, uw, iw, h1,
                                                       row_ptr_u, acol, aval, csr_cv);
    spmv_kernel<true, false><<<igrid, 256, 0, stream>>>(nullptr, uw, iw, h1,
                                                        row_ptr_i, acol, aval, csr_cv);
    // layer 2
    spmv_kernel<false, true><<<ugrid, 256, 0, stream>>>(h1, uw, iw, h2,
                                                        row_ptr_u, acol, aval, csr_cv);
    spmv_kernel<false, false><<<igrid, 256, 0, stream>>>(h1, uw, iw, h2,
                                                         row_ptr_i, acol, aval, csr_cv);
    // layer 3
    spmv_kernel<false, true><<<ugrid, 256, 0, stream>>>(h2, uw, iw, h3,
                                                        row_ptr_u, acol, aval, csr_cv);
    spmv_kernel<false, false><<<igrid, 256, 0, stream>>>(h2, uw, iw, h3,
                                                         row_ptr_i, acol, aval, csr_cv);

    ssq_kernel<<<SSQ_NBLK, 256, 0, stream>>>((const float4*)uw, (const float4*)iw,
                                             psq, N_USER_C * D_C / 4);
    score_kernel<<<SCORE_NBLK, 256, 0, stream>>>(x, uw, iw, h1, h2, h3, ploss);
    final_kernel<<<1, 256, 0, stream>>>(psq, ploss, (float*)d_out);
}

// Round 6
// 551.984 us; speedup vs baseline: 2.7737x; 1.1572x over previous
//
#include <hip/hip_runtime.h>
#include <hip/hip_bf16.h>

#define N_USER_C 100000
#define N_ITEM_C 100000
#define D_C 64
#define NN_C (N_USER_C + N_ITEM_C)
#define ND_C (NN_C * D_C)   /* 12,800,000 floats */

#define BSHIFT 8                                   /* 256 items per bucket */
#define NBUCKET ((N_ITEM_C + 255) >> BSHIFT)       /* 391 */
#define PB_CHUNK 8192

#define SSQ_NBLK 256
#define SCORE_NBLK 1024

// ---- item-side CSR via bucketed counting sort ------------------------------
// Item CSR is built from the FIRST half of the edge list only (second half is
// the symmetric mirror: arow[ne+e]=acol[e]+..., aval[ne+e]==aval[e]).

// Pass A: 391-bucket histogram (bucket = item_id >> 8).
__global__ __launch_bounds__(256) void bucket_count_kernel(
        const int* __restrict__ acol, int* __restrict__ bcnt, int ne) {
    __shared__ int s[NBUCKET];
    for (int i = threadIdx.x; i < NBUCKET; i += 256) s[i] = 0;
    __syncthreads();
    int stride = gridDim.x * blockDim.x;
    for (int e = blockIdx.x * blockDim.x + threadIdx.x; e < ne; e += stride)
        atomicAdd(&s[(acol[e] - N_USER_C) >> BSHIFT], 1);
    __syncthreads();
    for (int i = threadIdx.x; i < NBUCKET; i += 256)
        if (s[i]) atomicAdd(&bcnt[i], s[i]);
}

// exclusive scan of 391 bucket counts -> boff[0..391], boff[NBUCKET]=ne.
// Also seeds row_ptr_i[N_ITEM] = ne.
__global__ void bucket_scan_kernel(const int* __restrict__ bcnt, int* __restrict__ boff,
                                   int* __restrict__ row_ptr_i, int ne) {
    __shared__ int s[512];
    int t = threadIdx.x;
    s[t] = (t < NBUCKET) ? bcnt[t] : 0;
    __syncthreads();
    for (int o = 1; o < 512; o <<= 1) {
        int v = (t >= o) ? s[t - o] : 0;
        __syncthreads();
        s[t] += v;
        __syncthreads();
    }
    if (t < NBUCKET) boff[t] = (t == 0) ? 0 : s[t - 1];
    if (t == 0) { boff[NBUCKET] = ne; row_ptr_i[N_ITEM_C] = ne; }
}

// Pass B: per-block counting sort of PB_CHUNK-edge chunks into bucket-grouped
// staging. Each block's writes per bucket are CONTIGUOUS runs (good locality).
// Staging word0 = user(17b) | item_local(8b)<<24 ; word1 = val bits.
__global__ __launch_bounds__(256) void bucket_scatter_kernel(
        const int* __restrict__ arow, const int* __restrict__ acol,
        const float* __restrict__ aval, const int* __restrict__ boff,
        int* __restrict__ bfill, int2* __restrict__ staging, int ne) {
    __shared__ int hist[NBUCKET];
    __shared__ int base[NBUCKET];
    int nchunk = (ne + PB_CHUNK - 1) / PB_CHUNK;
    for (int ch = blockIdx.x; ch < nchunk; ch += gridDim.x) {
        int c0 = ch * PB_CHUNK;
        int c1 = c0 + PB_CHUNK; if (c1 > ne) c1 = ne;
        for (int i = threadIdx.x; i < NBUCKET; i += 256) hist[i] = 0;
        __syncthreads();
        for (int e = c0 + threadIdx.x; e < c1; e += 256)
            atomicAdd(&hist[(acol[e] - N_USER_C) >> BSHIFT], 1);
        __syncthreads();
        for (int i = threadIdx.x; i < NBUCKET; i += 256) {
            int h = hist[i];
            base[i] = h ? atomicAdd(&bfill[i], h) : 0;
            hist[i] = 0;                      // reuse as local fill
        }
        __syncthreads();
        for (int e = c0 + threadIdx.x; e < c1; e += 256) {
            int j = acol[e] - N_USER_C;
            int b = j >> BSHIFT;
            int p = atomicAdd(&hist[b], 1);
            staging[boff[b] + base[b] + p] =
                make_int2(arow[e] | ((j & 255) << 24), __float_as_int(aval[e]));
        }
        __syncthreads();
    }
}

// Pass C: one block per bucket. LDS histogram over the bucket's 256 items +
// LDS scan -> row_ptr_i (bucket base + local prefix), then in-L2 scatter to
// final item CSR (region ~32KB: lines fill before eviction).
__global__ __launch_bounds__(256) void bucket_finalize_kernel(
        const int2* __restrict__ staging, const int* __restrict__ boff,
        int* __restrict__ row_ptr_i, int2* __restrict__ csr_cv) {
    __shared__ int cnt[256];
    __shared__ int incl[256];
    int b = blockIdx.x, t = threadIdx.x;
    int s0 = boff[b], s1 = boff[b + 1];
    cnt[t] = 0;
    __syncthreads();
    for (int e = s0 + t; e < s1; e += 256)
        atomicAdd(&cnt[((unsigned)staging[e].x) >> 24], 1);
    __syncthreads();
    incl[t] = cnt[t];
    __syncthreads();
    for (int o = 1; o < 256; o <<= 1) {
        int v = (t >= o) ? incl[t - o] : 0;
        __syncthreads();
        incl[t] += v;
        __syncthreads();
    }
    int j = (b << BSHIFT) + t;
    if (j < N_ITEM_C) row_ptr_i[j] = s0 + ((t == 0) ? 0 : incl[t - 1]);
    cnt[t] = 0;                               // reuse as per-item fill
    __syncthreads();
    for (int e = s0 + t; e < s1; e += 256) {
        int2 w = staging[e];
        int jl = ((unsigned)w.x) >> 24;
        int p = atomicAdd(&cnt[jl], 1);
        int basej = (jl == 0) ? 0 : incl[jl - 1];
        csr_cv[s0 + basej + p] = make_int2(w.x & 0x00FFFFFF, w.y);
    }
}

// arow[0:ne] is sorted ascending (user ids). row_ptr_u[r] = first e with arow[e] >= r.
__global__ void user_rowptr_kernel(const int* __restrict__ arow, int* __restrict__ row_ptr_u,
                                   int ne) {
    int stride = gridDim.x * blockDim.x;
    for (int e = blockIdx.x * blockDim.x + threadIdx.x; e <= ne; e += stride) {
        int prev = (e == 0) ? -1 : arow[e - 1];
        int cur = (e == ne) ? N_USER_C : arow[e];
        for (int r = prev + 1; r <= cur; ++r) row_ptr_u[r] = e;
    }
}

// ---- propagation ----------------------------------------------------------

template <bool SPLIT, bool USER_ROWS>
__global__ __launch_bounds__(256) void spmv_kernel(
        const float* __restrict__ hin, const float* __restrict__ uw,
        const float* __restrict__ iw, float* __restrict__ hout,
        const int* __restrict__ row_ptr, const int* __restrict__ acol,
        const float* __restrict__ aval, const int2* __restrict__ csr_cv) {
    int gid = blockIdx.x * blockDim.x + threadIdx.x;
    int rr = gid >> 4;                         // local row within half
    int l = gid & 15;
    int nrows = USER_ROWS ? N_USER_C : N_ITEM_C;
    if (rr >= nrows) return;
    int e0 = row_ptr[rr], e1 = row_ptr[rr + 1];

    auto src = [&](int c) -> const float* {
        if (USER_ROWS) {  // c is a global item col id (>= N_USER)
            if (SPLIT) return iw + (size_t)(c - N_USER_C) * 64;
            return hin + (size_t)c * 64;
        } else {          // c is a user id (< N_USER)
            if (SPLIT) return uw + (size_t)c * 64;
            return hin + (size_t)c * 64;
        }
    };
    auto edge = [&](int e, int& c, float& v) {
        if (USER_ROWS) { c = acol[e]; v = aval[e]; }
        else { int2 cv = csr_cv[e]; c = cv.x; v = __int_as_float(cv.y); }
    };

    float4 a0 = {0, 0, 0, 0}, a1 = {0, 0, 0, 0}, a2 = {0, 0, 0, 0}, a3 = {0, 0, 0, 0};
    int e = e0;
    for (; e + 4 <= e1; e += 4) {
        int c0, c1, c2, c3; float v0, v1, v2, v3;
        edge(e, c0, v0); edge(e + 1, c1, v1); edge(e + 2, c2, v2); edge(e + 3, c3, v3);
        float4 h0 = *reinterpret_cast<const float4*>(src(c0) + l * 4);
        float4 h1 = *reinterpret_cast<const float4*>(src(c1) + l * 4);
        float4 h2 = *reinterpret_cast<const float4*>(src(c2) + l * 4);
        float4 h3 = *reinterpret_cast<const float4*>(src(c3) + l * 4);
        a0.x += v0 * h0.x; a0.y += v0 * h0.y; a0.z += v0 * h0.z; a0.w += v0 * h0.w;
        a1.x += v1 * h1.x; a1.y += v1 * h1.y; a1.z += v1 * h1.z; a1.w += v1 * h1.w;
        a2.x += v2 * h2.x; a2.y += v2 * h2.y; a2.z += v2 * h2.z; a2.w += v2 * h2.w;
        a3.x += v3 * h3.x; a3.y += v3 * h3.y; a3.z += v3 * h3.z; a3.w += v3 * h3.w;
    }
    for (; e < e1; ++e) {
        int c0; float v0;
        edge(e, c0, v0);
        float4 h0 = *reinterpret_cast<const float4*>(src(c0) + l * 4);
        a0.x += v0 * h0.x; a0.y += v0 * h0.y; a0.z += v0 * h0.z; a0.w += v0 * h0.w;
    }
    float4 acc;
    acc.x = (a0.x + a1.x) + (a2.x + a3.x);
    acc.y = (a0.y + a1.y) + (a2.y + a3.y);
    acc.z = (a0.z + a1.z) + (a2.z + a3.z);
    acc.w = (a0.w + a1.w) + (a2.w + a3.w);

    float ss = acc.x * acc.x + acc.y * acc.y + acc.z * acc.z + acc.w * acc.w;
    ss += __shfl_xor(ss, 1);
    ss += __shfl_xor(ss, 2);
    ss += __shfl_xor(ss, 4);
    ss += __shfl_xor(ss, 8);
    float scale = 1.0f / fmaxf(sqrtf(ss), 1e-12f);
    float4 hn = make_float4(acc.x * scale, acc.y * scale, acc.z * scale, acc.w * scale);
    size_t r = USER_ROWS ? rr : (N_USER_C + rr);
    *reinterpret_cast<float4*>(hout + r * 64 + l * 4) = hn;
}

// ---- losses (two-stage, atomic-free) ---------------------------------------

__global__ void ssq_kernel(const float4* __restrict__ uw, const float4* __restrict__ iw,
                           float2* __restrict__ partial_sq, int n4) {
    __shared__ float s_u[4], s_i[4];
    int stride = gridDim.x * blockDim.x;
    float su = 0.f, si = 0.f;
    int tot = 2 * n4;
    for (int i = blockIdx.x * blockDim.x + threadIdx.x; i < tot; i += stride) {
        float4 v = (i < n4) ? uw[i] : iw[i - n4];
        float d = v.x * v.x + v.y * v.y + v.z * v.z + v.w * v.w;
        if (i < n4) su += d; else si += d;
    }
    #pragma unroll
    for (int o = 1; o < 64; o <<= 1) { su += __shfl_xor(su, o); si += __shfl_xor(si, o); }
    int w = threadIdx.x >> 6;
    if ((threadIdx.x & 63) == 0) { s_u[w] = su; s_i[w] = si; }
    __syncthreads();
    if (threadIdx.x == 0) {
        float tu = s_u[0] + s_u[1] + s_u[2] + s_u[3];
        float ti = s_i[0] + s_i[1] + s_i[2] + s_i[3];
        partial_sq[blockIdx.x] = make_float2(tu, ti);
    }
}

__global__ void score_kernel(const int* __restrict__ x,
                             const float* __restrict__ uw, const float* __restrict__ iw,
                             const float* __restrict__ h1, const float* __restrict__ h2,
                             const float* __restrict__ h3, float* __restrict__ partial_loss) {
    __shared__ float s_l[4];
    int wave = threadIdx.x >> 6;
    int lane = threadIdx.x & 63;
    int b = blockIdx.x * 4 + wave;
    const int* xb = x + b * 24;          // (B, S=6, 4) int32

    auto emb = [&](int r) -> float {
        size_t o = (size_t)r * 64 + lane;
        float base = (r < N_USER_C) ? uw[o] : iw[o - (size_t)N_USER_C * 64];
        return base + 2.0f * h1[o] + 1.5f * h2[o] + (4.0f / 3.0f) * h3[o];
    };

    float t = emb(xb[0]) * emb(N_USER_C + xb[1]);
    #pragma unroll
    for (int s = 1; s <= 4; ++s)
        t -= emb(xb[s * 4]) * emb(N_USER_C + xb[s * 4 + 1]);

    #pragma unroll
    for (int o = 1; o < 64; o <<= 1) t += __shfl_xor(t, o);
    if (lane == 0) {
        float sig = 1.0f / (1.0f + expf(-t));
        s_l[wave] = -logf(1e-10f + sig);
    }
    __syncthreads();
    if (threadIdx.x == 0)
        partial_loss[blockIdx.x] = s_l[0] + s_l[1] + s_l[2] + s_l[3];
}

__global__ void final_kernel(const float2* __restrict__ partial_sq,
                             const float* __restrict__ partial_loss,
                             float* __restrict__ out) {
    __shared__ float s_u[4], s_i[4], s_l[4];
    int t = threadIdx.x;
    int w = t >> 6, lane = t & 63;

    float2 p = partial_sq[t];            // SSQ_NBLK == 256 == blockDim
    float su = p.x, si = p.y;
    float lo = 0.f;
    #pragma unroll
    for (int k = 0; k < SCORE_NBLK / 256; ++k) lo += partial_loss[t + k * 256];

    #pragma unroll
    for (int o = 1; o < 64; o <<= 1) {
        su += __shfl_xor(su, o);
        si += __shfl_xor(si, o);
        lo += __shfl_xor(lo, o);
    }
    if (lane == 0) { s_u[w] = su; s_i[w] = si; s_l[w] = lo; }
    __syncthreads();
    if (t == 0) {
        float tu = s_u[0] + s_u[1] + s_u[2] + s_u[3];
        float ti = s_i[0] + s_i[1] + s_i[2] + s_i[3];
        float tl = s_l[0] + s_l[1] + s_l[2] + s_l[3];
        float bpr = tl / 4096.0f;
        float emb_loss = (sqrtf(tu) + sqrtf(ti)) / (float)N_ITEM_C;
        out[0] = bpr + 1e-4f * emb_loss;
    }
}

// ---- launch ---------------------------------------------------------------

extern "C" void kernel_launch(void* const* d_in, const int* in_sizes, int n_in,
                              void* d_out, int out_size, void* d_ws, size_t ws_size,
                              hipStream_t stream) {
    const int*   x    = (const int*)d_in[0];
    const float* uw   = (const float*)d_in[1];
    const float* iw   = (const float*)d_in[2];
    const int*   arow = (const int*)d_in[3];
    const int*   acol = (const int*)d_in[4];
    const float* aval = (const float*)d_in[5];
    int nnz = in_sizes[3];
    int ne = nnz / 2;                     // edges per half

    char* ws = (char*)d_ws;
    size_t off = 0;
    auto alloc = [&](size_t bytes) -> void* {
        void* p = ws + off;
        off += bytes;
        off = (off + 255) & ~(size_t)255;
        return p;
    };
    float*  h1        = (float*)alloc((size_t)ND_C * 4);
    float*  h2        = (float*)alloc((size_t)ND_C * 4);
    float*  h3        = (float*)alloc((size_t)ND_C * 4);
    int2*   csr_cv    = (int2*)alloc((size_t)ne * 8);
    int*    row_ptr_u = (int*)alloc((size_t)(N_USER_C + 1) * 4);
    int*    row_ptr_i = (int*)alloc((size_t)(N_ITEM_C + 1) * 4);
    int*    bcnt      = (int*)alloc((size_t)NBUCKET * 4);
    int*    bfill     = (int*)alloc((size_t)NBUCKET * 4);
    int*    boff      = (int*)alloc((size_t)(NBUCKET + 1) * 4);
    float2* psq       = (float2*)alloc((size_t)SSQ_NBLK * 8);
    float*  ploss     = (float*)alloc((size_t)SCORE_NBLK * 4);
    // staging aliases h3: fully consumed by bucket_finalize before layer-3
    // spmv writes h3 (stream-ordered).
    int2*   staging   = (int2*)h3;

    hipMemsetAsync(bcnt, 0, (size_t)NBUCKET * 4, stream);
    hipMemsetAsync(bfill, 0, (size_t)NBUCKET * 4, stream);

    const int eb = 256;
    int egrid = (ne + eb - 1) / eb;
    if (egrid > 4096) egrid = 4096;

    bucket_count_kernel<<<256, 256, 0, stream>>>(acol, bcnt, ne);
    bucket_scan_kernel<<<1, 512, 0, stream>>>(bcnt, boff, row_ptr_i, ne);
    int nchunk = (ne + PB_CHUNK - 1) / PB_CHUNK;
    bucket_scatter_kernel<<<nchunk, 256, 0, stream>>>(arow, acol, aval, boff,
                                                      bfill, staging, ne);
    bucket_finalize_kernel<<<NBUCKET, 256, 0, stream>>>(staging, boff, row_ptr_i, csr_cv);
    user_rowptr_kernel<<<egrid, eb, 0, stream>>>(arow, row_ptr_u, ne);

    int ugrid = (N_USER_C * 16 + 255) / 256;   // 6250
    int igrid = (N_ITEM_C * 16 + 255) / 256;
    // layer 1 (reads raw weights)
    spmv_kernel<true, true><<<ugrid, 256, 0, stream>>>(nullptr, uw, iw, h1,
                                                       row_ptr_u, acol, aval, csr_cv);
    spmv_kernel<true, false><<<igrid, 256, 0, stream>>>(nullptr, uw, iw, h1,
                                                        row_ptr_i, acol, aval, csr_cv);
    // layer 2
    spmv_kernel<false, true><<<ugrid, 256, 0, stream>>>(h1, uw, iw, h2,
                                                        row_ptr_u, acol, aval, csr_cv);
    spmv_kernel<false, false><<<igrid, 256, 0, stream>>>(h1, uw, iw, h2,
                                                         row_ptr_i, acol, aval, csr_cv);
    // layer 3
    spmv_kernel<false, true><<<ugrid, 256, 0, stream>>>(h2, uw, iw, h3,
                                                        row_ptr_u, acol, aval, csr_cv);
    spmv_kernel<false, false><<<igrid, 256, 0, stream>>>(h2, uw, iw, h3,
                                                         row_ptr_i, acol, aval, csr_cv);

    ssq_kernel<<<SSQ_NBLK, 256, 0, stream>>>((const float4*)uw, (const float4*)iw,
                                             psq, N_USER_C * D_C / 4);
    score_kernel<<<SCORE_NBLK, 256, 0, stream>>>(x, uw, iw, h1, h2, h3, ploss);
    final_kernel<<<1, 256, 0, stream>>>(psq, ploss, (float*)d_out);
}

// Round 7
// 471.522 us; speedup vs baseline: 3.2470x; 1.1706x over previous
//
#include <hip/hip_runtime.h>
#include <hip/hip_bf16.h>

#define N_USER_C 100000
#define N_ITEM_C 100000
#define D_C 64
#define NN_C (N_USER_C + N_ITEM_C)
#define ND_C (NN_C * D_C)   /* 12,800,000 floats */

#define BSHIFT 8                                   /* 256 items per bucket */
#define NBUCKET ((N_ITEM_C + 255) >> BSHIFT)       /* 391 */
#define PB_CHUNK 8192

#define SSQ_NBLK 256
#define SCORE_NBLK 1024

// ---- item-side CSR via bucketed counting sort ------------------------------
// Built from the FIRST half of the edge list only (second half is the
// symmetric mirror with identical vals).

__global__ __launch_bounds__(256) void bucket_count_kernel(
        const int* __restrict__ acol, int* __restrict__ bcnt, int ne) {
    __shared__ int s[NBUCKET];
    for (int i = threadIdx.x; i < NBUCKET; i += 256) s[i] = 0;
    __syncthreads();
    int stride = gridDim.x * blockDim.x;
    for (int e = blockIdx.x * blockDim.x + threadIdx.x; e < ne; e += stride)
        atomicAdd(&s[(acol[e] - N_USER_C) >> BSHIFT], 1);
    __syncthreads();
    for (int i = threadIdx.x; i < NBUCKET; i += 256)
        if (s[i]) atomicAdd(&bcnt[i], s[i]);
}

__global__ void bucket_scan_kernel(const int* __restrict__ bcnt, int* __restrict__ boff,
                                   int* __restrict__ row_ptr_i, int ne) {
    __shared__ int s[512];
    int t = threadIdx.x;
    s[t] = (t < NBUCKET) ? bcnt[t] : 0;
    __syncthreads();
    for (int o = 1; o < 512; o <<= 1) {
        int v = (t >= o) ? s[t - o] : 0;
        __syncthreads();
        s[t] += v;
        __syncthreads();
    }
    if (t < NBUCKET) boff[t] = (t == 0) ? 0 : s[t - 1];
    if (t == 0) { boff[NBUCKET] = ne; row_ptr_i[N_ITEM_C] = ne; }
}

__global__ __launch_bounds__(256) void bucket_scatter_kernel(
        const int* __restrict__ arow, const int* __restrict__ acol,
        const float* __restrict__ aval, const int* __restrict__ boff,
        int* __restrict__ bfill, int2* __restrict__ staging, int ne) {
    __shared__ int hist[NBUCKET];
    __shared__ int base[NBUCKET];
    int nchunk = (ne + PB_CHUNK - 1) / PB_CHUNK;
    for (int ch = blockIdx.x; ch < nchunk; ch += gridDim.x) {
        int c0 = ch * PB_CHUNK;
        int c1 = c0 + PB_CHUNK; if (c1 > ne) c1 = ne;
        for (int i = threadIdx.x; i < NBUCKET; i += 256) hist[i] = 0;
        __syncthreads();
        for (int e = c0 + threadIdx.x; e < c1; e += 256)
            atomicAdd(&hist[(acol[e] - N_USER_C) >> BSHIFT], 1);
        __syncthreads();
        for (int i = threadIdx.x; i < NBUCKET; i += 256) {
            int h = hist[i];
            base[i] = h ? atomicAdd(&bfill[i], h) : 0;
            hist[i] = 0;                      // reuse as local fill
        }
        __syncthreads();
        for (int e = c0 + threadIdx.x; e < c1; e += 256) {
            int j = acol[e] - N_USER_C;
            int b = j >> BSHIFT;
            int p = atomicAdd(&hist[b], 1);
            staging[boff[b] + base[b] + p] =
                make_int2(arow[e] | ((j & 255) << 24), __float_as_int(aval[e]));
        }
        __syncthreads();
    }
}

__global__ __launch_bounds__(256) void bucket_finalize_kernel(
        const int2* __restrict__ staging, const int* __restrict__ boff,
        int* __restrict__ row_ptr_i, int2* __restrict__ csr_cv) {
    __shared__ int cnt[256];
    __shared__ int incl[256];
    int b = blockIdx.x, t = threadIdx.x;
    int s0 = boff[b], s1 = boff[b + 1];
    cnt[t] = 0;
    __syncthreads();
    for (int e = s0 + t; e < s1; e += 256)
        atomicAdd(&cnt[((unsigned)staging[e].x) >> 24], 1);
    __syncthreads();
    incl[t] = cnt[t];
    __syncthreads();
    for (int o = 1; o < 256; o <<= 1) {
        int v = (t >= o) ? incl[t - o] : 0;
        __syncthreads();
        incl[t] += v;
        __syncthreads();
    }
    int j = (b << BSHIFT) + t;
    if (j < N_ITEM_C) row_ptr_i[j] = s0 + ((t == 0) ? 0 : incl[t - 1]);
    cnt[t] = 0;                               // reuse as per-item fill
    __syncthreads();
    for (int e = s0 + t; e < s1; e += 256) {
        int2 w = staging[e];
        int jl = ((unsigned)w.x) >> 24;
        int p = atomicAdd(&cnt[jl], 1);
        int basej = (jl == 0) ? 0 : incl[jl - 1];
        csr_cv[s0 + basej + p] = make_int2(w.x & 0x00FFFFFF, w.y);
    }
}

__global__ void user_rowptr_kernel(const int* __restrict__ arow, int* __restrict__ row_ptr_u,
                                   int ne) {
    int stride = gridDim.x * blockDim.x;
    for (int e = blockIdx.x * blockDim.x + threadIdx.x; e <= ne; e += stride) {
        int prev = (e == 0) ? -1 : arow[e - 1];
        int cur = (e == ne) ? N_USER_C : arow[e];
        for (int r = prev + 1; r <= cur; ++r) row_ptr_u[r] = e;
    }
}

// Mark rows whose final embedding the loss actually reads (p + 4 negatives).
__global__ void flag_kernel(const int* __restrict__ x, int* __restrict__ flags) {
    int idx = blockIdx.x * blockDim.x + threadIdx.x;
    if (idx >= 4096 * 5) return;
    int b = idx / 5, s = idx % 5;
    const int* xb = x + b * 24;
    flags[xb[s * 4]] = 1;
    flags[N_USER_C + xb[s * 4 + 1]] = 1;
}

// ---- propagation ----------------------------------------------------------
// Merged user+item halves: row r<N_USER uses (row_ptr_u, acol, aval);
// else (row_ptr_i, csr_cv). SPARSE gates on flags (layer 3 only).

template <bool SPLIT, bool USER>
__device__ __forceinline__ float4 gather_row(
        int e0, int e1, int l, const float* __restrict__ hin,
        const float* __restrict__ uw, const float* __restrict__ iw,
        const int* __restrict__ acol, const float* __restrict__ aval,
        const int2* __restrict__ csr_cv) {
    auto src = [&](int c) -> const float* {
        if (USER) {   // c is a global item col id (>= N_USER)
            if (SPLIT) return iw + (size_t)(c - N_USER_C) * 64;
            return hin + (size_t)c * 64;
        } else {      // c is a user id (< N_USER)
            if (SPLIT) return uw + (size_t)c * 64;
            return hin + (size_t)c * 64;
        }
    };
    auto edge = [&](int e, int& c, float& v) {
        if (USER) { c = acol[e]; v = aval[e]; }
        else { int2 cv = csr_cv[e]; c = cv.x; v = __int_as_float(cv.y); }
    };
    float4 a0 = {0, 0, 0, 0}, a1 = {0, 0, 0, 0}, a2 = {0, 0, 0, 0}, a3 = {0, 0, 0, 0};
    int e = e0;
    for (; e + 4 <= e1; e += 4) {
        int c0, c1, c2, c3; float v0, v1, v2, v3;
        edge(e, c0, v0); edge(e + 1, c1, v1); edge(e + 2, c2, v2); edge(e + 3, c3, v3);
        float4 h0 = *reinterpret_cast<const float4*>(src(c0) + l * 4);
        float4 h1 = *reinterpret_cast<const float4*>(src(c1) + l * 4);
        float4 h2 = *reinterpret_cast<const float4*>(src(c2) + l * 4);
        float4 h3 = *reinterpret_cast<const float4*>(src(c3) + l * 4);
        a0.x += v0 * h0.x; a0.y += v0 * h0.y; a0.z += v0 * h0.z; a0.w += v0 * h0.w;
        a1.x += v1 * h1.x; a1.y += v1 * h1.y; a1.z += v1 * h1.z; a1.w += v1 * h1.w;
        a2.x += v2 * h2.x; a2.y += v2 * h2.y; a2.z += v2 * h2.z; a2.w += v2 * h2.w;
        a3.x += v3 * h3.x; a3.y += v3 * h3.y; a3.z += v3 * h3.z; a3.w += v3 * h3.w;
    }
    for (; e < e1; ++e) {
        int c0; float v0;
        edge(e, c0, v0);
        float4 h0 = *reinterpret_cast<const float4*>(src(c0) + l * 4);
        a0.x += v0 * h0.x; a0.y += v0 * h0.y; a0.z += v0 * h0.z; a0.w += v0 * h0.w;
    }
    float4 acc;
    acc.x = (a0.x + a1.x) + (a2.x + a3.x);
    acc.y = (a0.y + a1.y) + (a2.y + a3.y);
    acc.z = (a0.z + a1.z) + (a2.z + a3.z);
    acc.w = (a0.w + a1.w) + (a2.w + a3.w);
    return acc;
}

template <bool SPLIT, bool SPARSE>
__global__ __launch_bounds__(256) void spmv_kernel(
        const float* __restrict__ hin, const float* __restrict__ uw,
        const float* __restrict__ iw, float* __restrict__ hout,
        const int* __restrict__ row_ptr_u, const int* __restrict__ row_ptr_i,
        const int* __restrict__ acol, const float* __restrict__ aval,
        const int2* __restrict__ csr_cv, const int* __restrict__ flags) {
    int gid = blockIdx.x * blockDim.x + threadIdx.x;
    int r = gid >> 4;
    int l = gid & 15;
    if (r >= NN_C) return;
    if (SPARSE && flags[r] == 0) return;

    float4 acc;
    if (r < N_USER_C) {
        int e0 = row_ptr_u[r], e1 = row_ptr_u[r + 1];
        acc = gather_row<SPLIT, true>(e0, e1, l, hin, uw, iw, acol, aval, csr_cv);
    } else {
        int rr = r - N_USER_C;
        int e0 = row_ptr_i[rr], e1 = row_ptr_i[rr + 1];
        acc = gather_row<SPLIT, false>(e0, e1, l, hin, uw, iw, acol, aval, csr_cv);
    }

    float ss = acc.x * acc.x + acc.y * acc.y + acc.z * acc.z + acc.w * acc.w;
    ss += __shfl_xor(ss, 1);
    ss += __shfl_xor(ss, 2);
    ss += __shfl_xor(ss, 4);
    ss += __shfl_xor(ss, 8);
    float scale = 1.0f / fmaxf(sqrtf(ss), 1e-12f);
    float4 hn = make_float4(acc.x * scale, acc.y * scale, acc.z * scale, acc.w * scale);
    *reinterpret_cast<float4*>(hout + (size_t)r * 64 + l * 4) = hn;
}

// ---- losses (two-stage, atomic-free) ---------------------------------------

__global__ void ssq_kernel(const float4* __restrict__ uw, const float4* __restrict__ iw,
                           float2* __restrict__ partial_sq, int n4) {
    __shared__ float s_u[4], s_i[4];
    int stride = gridDim.x * blockDim.x;
    float su = 0.f, si = 0.f;
    int tot = 2 * n4;
    for (int i = blockIdx.x * blockDim.x + threadIdx.x; i < tot; i += stride) {
        float4 v = (i < n4) ? uw[i] : iw[i - n4];
        float d = v.x * v.x + v.y * v.y + v.z * v.z + v.w * v.w;
        if (i < n4) su += d; else si += d;
    }
    #pragma unroll
    for (int o = 1; o < 64; o <<= 1) { su += __shfl_xor(su, o); si += __shfl_xor(si, o); }
    int w = threadIdx.x >> 6;
    if ((threadIdx.x & 63) == 0) { s_u[w] = su; s_i[w] = si; }
    __syncthreads();
    if (threadIdx.x == 0) {
        float tu = s_u[0] + s_u[1] + s_u[2] + s_u[3];
        float ti = s_i[0] + s_i[1] + s_i[2] + s_i[3];
        partial_sq[blockIdx.x] = make_float2(tu, ti);
    }
}

__global__ void score_kernel(const int* __restrict__ x,
                             const float* __restrict__ uw, const float* __restrict__ iw,
                             const float* __restrict__ h1, const float* __restrict__ h2,
                             const float* __restrict__ h3, float* __restrict__ partial_loss) {
    __shared__ float s_l[4];
    int wave = threadIdx.x >> 6;
    int lane = threadIdx.x & 63;
    int b = blockIdx.x * 4 + wave;
    const int* xb = x + b * 24;          // (B, S=6, 4) int32

    auto emb = [&](int r) -> float {
        size_t o = (size_t)r * 64 + lane;
        float base = (r < N_USER_C) ? uw[o] : iw[o - (size_t)N_USER_C * 64];
        return base + 2.0f * h1[o] + 1.5f * h2[o] + (4.0f / 3.0f) * h3[o];
    };

    float t = emb(xb[0]) * emb(N_USER_C + xb[1]);
    #pragma unroll
    for (int s = 1; s <= 4; ++s)
        t -= emb(xb[s * 4]) * emb(N_USER_C + xb[s * 4 + 1]);

    #pragma unroll
    for (int o = 1; o < 64; o <<= 1) t += __shfl_xor(t, o);
    if (lane == 0) {
        float sig = 1.0f / (1.0f + expf(-t));
        s_l[wave] = -logf(1e-10f + sig);
    }
    __syncthreads();
    if (threadIdx.x == 0)
        partial_loss[blockIdx.x] = s_l[0] + s_l[1] + s_l[2] + s_l[3];
}

__global__ void final_kernel(const float2* __restrict__ partial_sq,
                             const float* __restrict__ partial_loss,
                             float* __restrict__ out) {
    __shared__ float s_u[4], s_i[4], s_l[4];
    int t = threadIdx.x;
    int w = t >> 6, lane = t & 63;

    float2 p = partial_sq[t];            // SSQ_NBLK == 256 == blockDim
    float su = p.x, si = p.y;
    float lo = 0.f;
    #pragma unroll
    for (int k = 0; k < SCORE_NBLK / 256; ++k) lo += partial_loss[t + k * 256];

    #pragma unroll
    for (int o = 1; o < 64; o <<= 1) {
        su += __shfl_xor(su, o);
        si += __shfl_xor(si, o);
        lo += __shfl_xor(lo, o);
    }
    if (lane == 0) { s_u[w] = su; s_i[w] = si; s_l[w] = lo; }
    __syncthreads();
    if (t == 0) {
        float tu = s_u[0] + s_u[1] + s_u[2] + s_u[3];
        float ti = s_i[0] + s_i[1] + s_i[2] + s_i[3];
        float tl = s_l[0] + s_l[1] + s_l[2] + s_l[3];
        float bpr = tl / 4096.0f;
        float emb_loss = (sqrtf(tu) + sqrtf(ti)) / (float)N_ITEM_C;
        out[0] = bpr + 1e-4f * emb_loss;
    }
}

// ---- launch ---------------------------------------------------------------

extern "C" void kernel_launch(void* const* d_in, const int* in_sizes, int n_in,
                              void* d_out, int out_size, void* d_ws, size_t ws_size,
                              hipStream_t stream) {
    const int*   x    = (const int*)d_in[0];
    const float* uw   = (const float*)d_in[1];
    const float* iw   = (const float*)d_in[2];
    const int*   arow = (const int*)d_in[3];
    const int*   acol = (const int*)d_in[4];
    const float* aval = (const float*)d_in[5];
    int nnz = in_sizes[3];
    int ne = nnz / 2;                     // edges per half

    char* ws = (char*)d_ws;
    size_t off = 0;
    auto alloc = [&](size_t bytes) -> void* {
        void* p = ws + off;
        off += bytes;
        off = (off + 255) & ~(size_t)255;
        return p;
    };
    float*  h1        = (float*)alloc((size_t)ND_C * 4);
    float*  h2        = (float*)alloc((size_t)ND_C * 4);
    float*  h3        = (float*)alloc((size_t)ND_C * 4);
    int2*   csr_cv    = (int2*)alloc((size_t)ne * 8);
    int*    row_ptr_u = (int*)alloc((size_t)(N_USER_C + 1) * 4);
    int*    row_ptr_i = (int*)alloc((size_t)(N_ITEM_C + 1) * 4);
    int*    flags     = (int*)alloc((size_t)NN_C * 4);
    int*    bcnt      = (int*)alloc((size_t)NBUCKET * 4);
    int*    bfill     = (int*)alloc((size_t)NBUCKET * 4);
    int*    boff      = (int*)alloc((size_t)(NBUCKET + 1) * 4);
    float2* psq       = (float2*)alloc((size_t)SSQ_NBLK * 8);
    float*  ploss     = (float*)alloc((size_t)SCORE_NBLK * 4);
    // staging aliases h3: fully consumed by bucket_finalize before layer-3
    // spmv writes h3 (stream-ordered).
    int2*   staging   = (int2*)h3;

    hipMemsetAsync(bcnt, 0, (size_t)NBUCKET * 4, stream);
    hipMemsetAsync(bfill, 0, (size_t)NBUCKET * 4, stream);
    hipMemsetAsync(flags, 0, (size_t)NN_C * 4, stream);

    const int eb = 256;
    int egrid = (ne + eb - 1) / eb;
    if (egrid > 4096) egrid = 4096;

    bucket_count_kernel<<<256, 256, 0, stream>>>(acol, bcnt, ne);
    bucket_scan_kernel<<<1, 512, 0, stream>>>(bcnt, boff, row_ptr_i, ne);
    int nchunk = (ne + PB_CHUNK - 1) / PB_CHUNK;
    bucket_scatter_kernel<<<nchunk, 256, 0, stream>>>(arow, acol, aval, boff,
                                                      bfill, staging, ne);
    bucket_finalize_kernel<<<NBUCKET, 256, 0, stream>>>(staging, boff, row_ptr_i, csr_cv);
    user_rowptr_kernel<<<egrid, eb, 0, stream>>>(arow, row_ptr_u, ne);
    flag_kernel<<<80, 256, 0, stream>>>(x, flags);

    int grid = (NN_C * 16 + 255) / 256;   // 12500 blocks
    spmv_kernel<true, false><<<grid, 256, 0, stream>>>(nullptr, uw, iw, h1,
        row_ptr_u, row_ptr_i, acol, aval, csr_cv, flags);
    spmv_kernel<false, false><<<grid, 256, 0, stream>>>(h1, uw, iw, h2,
        row_ptr_u, row_ptr_i, acol, aval, csr_cv, flags);
    spmv_kernel<false, true><<<grid, 256, 0, stream>>>(h2, uw, iw, h3,
        row_ptr_u, row_ptr_i, acol, aval, csr_cv, flags);

    ssq_kernel<<<SSQ_NBLK, 256, 0, stream>>>((const float4*)uw, (const float4*)iw,
                                             psq, N_USER_C * D_C / 4);
    score_kernel<<<SCORE_NBLK, 256, 0, stream>>>(x, uw, iw, h1, h2, h3, ploss);
    final_kernel<<<1, 256, 0, stream>>>(psq, ploss, (float*)d_out);
}